// Round 6
// baseline (794.064 us; speedup 1.0000x reference)
//
#include <hip/hip_runtime.h>
#include <stdint.h>

typedef unsigned short u16;
typedef __bf16 bf16x8 __attribute__((ext_vector_type(8)));
typedef float f32x4 __attribute__((ext_vector_type(4)));
typedef u16 u16x4 __attribute__((ext_vector_type(4)));
typedef u16 u16x8 __attribute__((ext_vector_type(8)));

__device__ __forceinline__ u16 f2b(float f) {  // fp32 -> bf16 bits, RNE
    unsigned u = __builtin_bit_cast(unsigned, f);
    u = u + 0x7FFFu + ((u >> 16) & 1u);
    return (u16)(u >> 16);
}
__device__ __forceinline__ float b2f(u16 b) {
    return __builtin_bit_cast(float, (unsigned)b << 16);
}

// async global->LDS, 16B per lane. LDS dest = wave-uniform base + lane*16.
__device__ __forceinline__ void glds16(const u16* g, u16* l) {
    __builtin_amdgcn_global_load_lds(
        (const __attribute__((address_space(1))) void*)g,
        (__attribute__((address_space(3))) void*)l,
        16, 0, 0);
}

template <int N> __device__ __forceinline__ void waitvm() {
    if constexpr (N == 0)      asm volatile("s_waitcnt vmcnt(0)" ::: "memory");
    else if constexpr (N == 2) asm volatile("s_waitcnt vmcnt(2)" ::: "memory");
    else if constexpr (N == 3) asm volatile("s_waitcnt vmcnt(3)" ::: "memory");
    else if constexpr (N == 4) asm volatile("s_waitcnt vmcnt(4)" ::: "memory");
    else if constexpr (N == 6) asm volatile("s_waitcnt vmcnt(6)" ::: "memory");
    else if constexpr (N == 8) asm volatile("s_waitcnt vmcnt(8)" ::: "memory");
}

// ---------------------------------------------------------------- fused cast fp32->bf16
// One launch for all 5 weight/activation regions (saves 4 launch+tail overheads).
__global__ __launch_bounds__(256) void cast_all(const float* __restrict__ h,
                                                const float* __restrict__ wq,
                                                const float* __restrict__ wk,
                                                const float* __restrict__ wv,
                                                const float* __restrict__ wo,
                                                u16* __restrict__ h_bf,
                                                u16* __restrict__ wqk_bf,
                                                u16* __restrict__ wv_bf,
                                                u16* __restrict__ wo_bf) {
    const long total  = 35651584;  // elems
    const long stride = (long)gridDim.x * 256 * 4;
    for (long i = ((long)blockIdx.x * 256 + threadIdx.x) * 4; i < total; i += stride) {
        const float* s; u16* d; long off;
        if (i < 8388608)        { s = h;  d = h_bf;             off = i; }
        else if (i < 25165824)  { s = wq; d = wqk_bf;           off = i - 8388608; }
        else if (i < 26214400)  { s = wk; d = wqk_bf + 16777216; off = i - 25165824; }
        else if (i < 27262976)  { s = wv; d = wv_bf;            off = i - 26214400; }
        else                    { s = wo; d = wo_bf;            off = i - 27262976; }
        f32x4 v = *(const f32x4*)(s + off);
        u16x4 o;
        o.x = f2b(v.x); o.y = f2b(v.y); o.z = f2b(v.z); o.w = f2b(v.w);
        *(u16x4*)(d + off) = o;
    }
}

// ---------------------------------------------------------------- GEMM C = A * Bt^T  (legacy 128x128)
// Kept for the small v_t GEMM (M=512) where the big-tile kernel can't fill the grid.
template <int OUT_BF16>
__global__ __launch_bounds__(256) void gemm_bt(const u16* __restrict__ A,
                                               const u16* __restrict__ Bt,
                                               void* __restrict__ Cout,
                                               int M, int N, int K) {
    __shared__ u16 As[128 * 32];
    __shared__ u16 Bs[128 * 32];
    const int tid  = threadIdx.x;
    const int w    = tid >> 6;
    const int lane = tid & 63;
    const int quad = lane >> 4;
    const int ml   = lane & 15;
    const long bm  = (long)blockIdx.y * 128;
    const long bn  = (long)blockIdx.x * 128;
    const int wm   = (w >> 1) * 64;
    const int wn   = (w & 1) * 64;
    const int grow = lane >> 2;
    const int gcol = (lane & 3) * 8;

    const u16* Ag = A  + (bm + w * 16 + grow) * (long)K + gcol;
    const u16* Bg = Bt + (bn + w * 16 + grow) * (long)K + gcol;
    u16* lAs0 = &As[(w * 16) * 32];
    u16* lAs1 = &As[(64 + w * 16) * 32];
    u16* lBs0 = &Bs[(w * 16) * 32];
    u16* lBs1 = &Bs[(64 + w * 16) * 32];

    const f32x4 fz = {0.f, 0.f, 0.f, 0.f};
    f32x4 acc[4][4];
#pragma unroll
    for (int i = 0; i < 4; ++i)
#pragma unroll
        for (int j = 0; j < 4; ++j) acc[i][j] = fz;

    for (int k0 = 0; k0 < K; k0 += 32) {
        __syncthreads();
        glds16(Ag + k0,                lAs0);
        glds16(Ag + 64 * (long)K + k0, lAs1);
        glds16(Bg + k0,                lBs0);
        glds16(Bg + 64 * (long)K + k0, lBs1);
        __builtin_amdgcn_s_waitcnt(0);
        __syncthreads();
        bf16x8 af[4], bfr[4];
#pragma unroll
        for (int mt = 0; mt < 4; ++mt)
            af[mt] = *(const bf16x8*)&As[(wm + mt * 16 + ml) * 32 + quad * 8];
#pragma unroll
        for (int nt = 0; nt < 4; ++nt)
            bfr[nt] = *(const bf16x8*)&Bs[(wn + nt * 16 + ml) * 32 + quad * 8];
#pragma unroll
        for (int mt = 0; mt < 4; ++mt)
#pragma unroll
            for (int nt = 0; nt < 4; ++nt)
                acc[mt][nt] = __builtin_amdgcn_mfma_f32_16x16x32_bf16(
                    af[mt], bfr[nt], acc[mt][nt], 0, 0, 0);
    }
#pragma unroll
    for (int mt = 0; mt < 4; ++mt)
#pragma unroll
        for (int nt = 0; nt < 4; ++nt)
#pragma unroll
            for (int r = 0; r < 4; ++r) {
                long row = bm + wm + mt * 16 + quad * 4 + r;
                long col = bn + wn + nt * 16 + ml;
                float v = acc[mt][nt][r];
                if (OUT_BF16) ((u16*)Cout)[row * N + col] = f2b(v);
                else          ((float*)Cout)[row * N + col] = v;
            }
}

// ---------------------------------------------------------------- GEMM pipe v2: ring-3, lead-2, 1 barrier/step
// (unchanged from round 5 -- verified: FETCH 144MB, conflicts 0, 862 TF)
template <int OUT_BF16, int BN>
__global__ __launch_bounds__(512, 4) void gemm_pipe(const u16* __restrict__ A,
                                                    const u16* __restrict__ Bt,
                                                    void* __restrict__ Cout,
                                                    int M, int N, int K, int nbx) {
    (void)M;
    constexpr int NF  = BN / 64;
    constexpr int ASZ = 128 * 32;
    constexpr int BSZ = BN * 32;
    constexpr int LPT = 1 + BN / 128;
    __shared__ u16 sm[3][ASZ + BSZ];

    const int tid  = threadIdx.x;
    const int w    = tid >> 6;
    const int lane = tid & 63;
    const int quad = lane >> 4;
    const int ml   = lane & 15;
    const int wm   = (w >> 2) * 64;
    const int wn   = (w & 3) * (BN / 4);

    const int nwg = gridDim.x;
    const int q8 = nwg >> 3, r8 = nwg & 7;
    const int xcd = blockIdx.x & 7, loc = blockIdx.x >> 3;
    const int wg  = (xcd < r8 ? xcd * (q8 + 1) : r8 * (q8 + 1) + (xcd - r8) * q8) + loc;
    const int per = nbx * 8;
    const int gid = wg / per, win = wg % per;
    const long bm = (long)(gid * 8 + (win & 7)) * 128;
    const long bn = (long)(win >> 3) * BN;

    const int  srow = w * 16 + (lane >> 2);
    const int  scc  = (lane & 3) ^ ((lane >> 3) & 3);
    const u16* Ag0  = A  + (bm + srow) * (long)K + scc * 8;
    const u16* Bg0  = Bt + (bn + srow) * (long)K + scc * 8;
    const u16* Bg1  = (BN == 256) ? Bg0 + 128 * (long)K : Bg0;
    const int  ldsw = w * 512;

    const int ccr  = quad ^ ((ml >> 1) & 3);
    const int aoff = (wm + ml) * 32 + ccr * 8;
    const int boff = (wn + ml) * 32 + ccr * 8;

    const f32x4 fz = {0.f, 0.f, 0.f, 0.f};
    f32x4 acc[4][NF];
#pragma unroll
    for (int i = 0; i < 4; ++i)
#pragma unroll
        for (int j = 0; j < NF; ++j) acc[i][j] = fz;

    const int NT = K >> 5;

#define STAGE(tt)                                                      \
    {                                                                  \
        u16* base = &sm[(tt) % 3][0];                                  \
        const long ko = (long)(tt) * 32;                               \
        glds16(Ag0 + ko, base + ldsw);                                 \
        glds16(Bg0 + ko, base + ASZ + ldsw);                           \
        if (BN == 256) glds16(Bg1 + ko, base + ASZ + 4096 + ldsw);     \
    }

    STAGE(0); STAGE(1);

    for (int t = 0; t < NT; ++t) {
        if (t + 1 < NT) waitvm<LPT>();
        else            waitvm<0>();
        __builtin_amdgcn_s_barrier();
        __builtin_amdgcn_sched_barrier(0);
        if (t + 2 < NT) STAGE(t + 2);

        const u16* Ab = &sm[t % 3][0];
        const u16* Bb = Ab + ASZ;
        bf16x8 af[4], bfr[NF];
#pragma unroll
        for (int mt = 0; mt < 4; ++mt)
            af[mt] = *(const bf16x8*)(Ab + aoff + mt * 512);
#pragma unroll
        for (int nt = 0; nt < NF; ++nt)
            bfr[nt] = *(const bf16x8*)(Bb + boff + nt * 512);

        __builtin_amdgcn_s_setprio(1);
#pragma unroll
        for (int mt = 0; mt < 4; ++mt)
#pragma unroll
            for (int nt = 0; nt < NF; ++nt)
                acc[mt][nt] = __builtin_amdgcn_mfma_f32_16x16x32_bf16(
                    af[mt], bfr[nt], acc[mt][nt], 0, 0, 0);
        __builtin_amdgcn_s_setprio(0);
    }
#undef STAGE

#pragma unroll
    for (int mt = 0; mt < 4; ++mt)
#pragma unroll
        for (int nt = 0; nt < NF; ++nt)
#pragma unroll
            for (int r = 0; r < 4; ++r) {
                long row = bm + wm + mt * 16 + quad * 4 + r;
                long col = bn + wn + nt * 16 + ml;
                float v = acc[mt][nt][r];
                if (OUT_BF16) ((u16*)Cout)[row * N + col] = f2b(v);
                else          ((float*)Cout)[row * N + col] = v;
            }
}

// ---------------------------------------------------------------- RMSNorm + RoPE + relayout
// 256 threads = 4 waves, each wave one token (4x fewer launches than 64-thread blocks).
__global__ __launch_bounds__(256) void norm_rope(const u16* __restrict__ qgk,
                                                 const float* __restrict__ cosp,
                                                 const float* __restrict__ sinp,
                                                 const float* __restrict__ qw,
                                                 const float* __restrict__ kw,
                                                 u16* __restrict__ qf,
                                                 u16* __restrict__ kf) {
    const int t = blockIdx.x * 4 + (threadIdx.x >> 6);
    const int u = blockIdx.y;
    const int lane = threadIdx.x & 63;
    const int b = t >> 11, s = t & 2047;
    const u16* src; const float* wgt; u16* dst;
    if (u < 16) {
        src = qgk + (long)t * 8704 + u * 512;
        wgt = qw;
        dst = qf + ((long)(b * 16 + u) * 2048 + s) * 256;
    } else {
        int kh = u - 16;
        src = qgk + (long)t * 8704 + 8192 + kh * 256;
        wgt = kw;
        dst = kf + ((long)(b * 2 + kh) * 2048 + s) * 256;
    }
    const int d0 = lane * 4;
    u16x4 raw = *(const u16x4*)(src + d0);
    float x0 = b2f(raw.x), x1 = b2f(raw.y), x2 = b2f(raw.z), x3 = b2f(raw.w);
    float ss = x0 * x0 + x1 * x1 + x2 * x2 + x3 * x3;
    for (int off = 32; off; off >>= 1) ss += __shfl_xor(ss, off, 64);
    float inv = rsqrtf(ss * (1.0f / 256.0f) + 1e-6f);
    float n0 = x0 * inv * wgt[d0 + 0];
    float n1 = x1 * inv * wgt[d0 + 1];
    float n2 = x2 * inv * wgt[d0 + 2];
    float n3 = x3 * inv * wgt[d0 + 3];
    float p0 = __shfl_xor(n0, 8, 64);
    float p1 = __shfl_xor(n1, 8, 64);
    float p2 = __shfl_xor(n2, 8, 64);
    float p3 = __shfl_xor(n3, 8, 64);
    if (lane < 16) {
        f32x4 c  = *(const f32x4*)(cosp + (long)t * 64 + d0);
        f32x4 sn = *(const f32x4*)(sinp + (long)t * 64 + d0);
        float sgn = (lane < 8) ? -1.f : 1.f;
        n0 = n0 * c[0] + sgn * p0 * sn[0];
        n1 = n1 * c[1] + sgn * p1 * sn[1];
        n2 = n2 * c[2] + sgn * p2 * sn[2];
        n3 = n3 * c[3] + sgn * p3 * sn[3];
    }
    const float qs = (u < 16) ? 0.0625f : 1.0f;
    n0 *= qs; n1 *= qs; n2 *= qs; n3 *= qs;
    u16x4 o;
    o.x = f2b(n0); o.y = f2b(n1); o.z = f2b(n2); o.w = f2b(n3);
    *(u16x4*)(dst + d0) = o;
}

// ---------------------------------------------------------------- flash attention + gate (v3: QBLK=128)
// 512 threads = 8 waves (2 q-halves x 4 sub-tiles); each staged K/V tile feeds 128
// q-rows (staging glds, barriers, LDS writes per FLOP all halved vs QBLK=64).
// Grid 512 = exactly 2 blocks/CU x 256 CU (one residency round). LDS 80 KiB.
// Same verified two-phase tile schedule and XOR swizzle (rule #21) as v2:
// issue K(4)+V(4) glds -> vmcnt(4)+barrier -> QK (V in flight) -> vmcnt(0)+barrier -> PV.
// Causal: wave's diagonal tile dtile = 2*qt + (w>>2); kt > dtile fully masked (~3% waste).
__global__ __launch_bounds__(512, 4) void attn_fused(const u16* __restrict__ qf,
                                                     const u16* __restrict__ kf,
                                                     const u16* __restrict__ vt,
                                                     const u16* __restrict__ qgk,
                                                     u16* __restrict__ attn_g) {
    __shared__ u16 Ks[64 * 256];    // [key][d]   32 KiB, swizzled
    __shared__ u16 Vt[256 * 64];    // [d][key]   32 KiB, swizzled
    __shared__ u16 P[128 * 64];     // [q][key]   16 KiB, swizzled, wave-private rows
    const int flat = blockIdx.x;
    const int qt = 15 - (flat >> 5);   // LPT: heavy q-tiles first
    const int h  = flat & 15;
    const int b  = (flat >> 4) & 1;
    const int kh = h >> 3;             // GQA rep = 8
    const int tid = threadIdx.x;
    const int w = tid >> 6, lane = tid & 63;
    const int quad = lane >> 4, ml = lane & 15;
    const int wh = w >> 2, wq = w & 3;
    const int qrow = qt * 128 + wh * 64 + wq * 16;
    const int dtile = 2 * qt + wh;     // this wave's diagonal k-tile index

    const u16* qptr = qf + ((long)(b * 16 + h) * 2048 + qrow + ml) * 256;
    bf16x8 qfrag[8];
#pragma unroll
    for (int dd = 0; dd < 8; ++dd)
        qfrag[dd] = *(const bf16x8*)(qptr + dd * 32 + quad * 8);

    const f32x4 fz = {0.f, 0.f, 0.f, 0.f};
    f32x4 oacc[16];
#pragma unroll
    for (int i = 0; i < 16; ++i) oacc[i] = fz;
    float lsum[4] = {0.f, 0.f, 0.f, 0.f};

    const u16* kbp = kf + (long)(b * 2 + kh) * 2048 * 256;
    const u16* vbp = vt + (long)kh * 256 * 4096 + (long)b * 2048;

    // staging: chunk c = i*512 + tid (16B chunks). K: row=c>>5, cc=c&31.
    // V: drow=c>>3, kc=c&7. Swizzled SOURCE (rule #21), linear LDS dest.
    const int krow7 = (tid >> 5) & 7;            // K row & 7 (i*16 preserves mod 8)
    const int kswz  = (tid & 31) ^ krow7;
    const int vrow7 = (tid >> 3) & 7;            // V drow & 7 (i*64 preserves mod 8)
    const int vswz  = (tid & 7) ^ vrow7;
    const int krow  = tid >> 5;                  // 0..15 within issue
    const int vrow  = tid >> 3;                  // 0..63 within issue

    const int m7 = ml & 7;

    const int nkt = 2 * qt + 2;  // causal: tiles 0 .. 2qt+1
    for (int kt = 0; kt < nkt; ++kt) {
        const int kb = kt * 64;
        __syncthreads();   // all waves done reading Ks/Vt/P of previous tile
#pragma unroll
        for (int i = 0; i < 4; ++i)
            glds16(kbp + (long)(kb + i * 16 + krow) * 256 + kswz * 8,
                   Ks + i * 4096 + w * 512);
#pragma unroll
        for (int i = 0; i < 4; ++i)
            glds16(vbp + (long)(i * 64 + vrow) * 4096 + kb + vswz * 8,
                   Vt + i * 4096 + w * 512);
        waitvm<4>();                        // own K loads done (V still in flight)
        __builtin_amdgcn_s_barrier();       // all waves' K done -> Ks readable
        __builtin_amdgcn_sched_barrier(0);

        // ---- S = Q K^T (pre-scaled q => sacc is the final score)
        f32x4 sacc[4];
#pragma unroll
        for (int i = 0; i < 4; ++i) sacc[i] = fz;
#pragma unroll
        for (int dd = 0; dd < 8; ++dd) {
            const int ck = (dd * 4 + quad) ^ m7;
            bf16x8 kf0 = *(const bf16x8*)&Ks[(0 * 16 + ml) * 256 + ck * 8];
            bf16x8 kf1 = *(const bf16x8*)&Ks[(1 * 16 + ml) * 256 + ck * 8];
            bf16x8 kf2 = *(const bf16x8*)&Ks[(2 * 16 + ml) * 256 + ck * 8];
            bf16x8 kf3 = *(const bf16x8*)&Ks[(3 * 16 + ml) * 256 + ck * 8];
            __builtin_amdgcn_s_setprio(1);
            sacc[0] = __builtin_amdgcn_mfma_f32_16x16x32_bf16(qfrag[dd], kf0, sacc[0], 0, 0, 0);
            sacc[1] = __builtin_amdgcn_mfma_f32_16x16x32_bf16(qfrag[dd], kf1, sacc[1], 0, 0, 0);
            sacc[2] = __builtin_amdgcn_mfma_f32_16x16x32_bf16(qfrag[dd], kf2, sacc[2], 0, 0, 0);
            sacc[3] = __builtin_amdgcn_mfma_f32_16x16x32_bf16(qfrag[dd], kf3, sacc[3], 0, 0, 0);
            __builtin_amdgcn_s_setprio(0);
        }

        // ---- fixed-shift softmax: p = exp(s - 16), no shuffles, no rescale
        const bool maskt = (kt >= dtile);
#pragma unroll
        for (int nt = 0; nt < 4; ++nt)
#pragma unroll
            for (int r = 0; r < 4; ++r) {
                float sv = sacc[nt][r];
                if (maskt) {
                    int rel = wq * 16 + quad * 4 + r + (dtile - kt) * 64;
                    sv = (nt * 16 + ml > rel) ? -1e30f : sv;
                }
                float pv = __expf(sv - 16.0f);
                lsum[r] += pv;
                const int prow = w * 16 + quad * 4 + r;
                const int chk = (nt * 2 + (ml >> 3)) ^ ((quad * 4 + r) & 7);
                P[prow * 64 + chk * 8 + m7] = f2b(pv);
            }

        waitvm<0>();                        // own V loads done
        __builtin_amdgcn_s_barrier();       // all waves' V done -> Vt readable
        __builtin_amdgcn_sched_barrier(0);

        // ---- O += P V   (P rows wave-private; lgkm deps ordered by compiler)
#pragma unroll
        for (int ks = 0; ks < 2; ++ks) {
            const int ck = (ks * 4 + quad) ^ m7;
            bf16x8 pfrag = *(const bf16x8*)&P[(w * 16 + ml) * 64 + ck * 8];
            __builtin_amdgcn_s_setprio(1);
#pragma unroll
            for (int dt = 0; dt < 16; ++dt) {
                bf16x8 vfrag = *(const bf16x8*)&Vt[(dt * 16 + ml) * 64 + ck * 8];
                oacc[dt] = __builtin_amdgcn_mfma_f32_16x16x32_bf16(pfrag, vfrag, oacc[dt], 0, 0, 0);
            }
            __builtin_amdgcn_s_setprio(0);
        }
    }

    // ---- single deferred row-sum reduction (16 lanes of each quad share a row)
#pragma unroll
    for (int off = 1; off < 16; off <<= 1)
#pragma unroll
        for (int r = 0; r < 4; ++r) lsum[r] += __shfl_xor(lsum[r], off, 64);

    // ---- epilogue: 1/l, sigmoid gate, store bf16 (4096 x 4096, col = h*256+d)
#pragma unroll
    for (int dt = 0; dt < 16; ++dt)
#pragma unroll
        for (int r = 0; r < 4; ++r) {
            int srow = qrow + quad * 4 + r;
            long tok = (long)b * 2048 + srow;
            int d = dt * 16 + ml;
            float o = oacc[dt][r] / lsum[r];
            float g = b2f(qgk[tok * 8704 + h * 512 + 256 + d]);
            float gv = o / (1.f + __expf(-g));
            attn_g[tok * 4096 + h * 256 + d] = f2b(gv);
        }
}

// ---------------------------------------------------------------- launch
extern "C" void kernel_launch(void* const* d_in, const int* in_sizes, int n_in,
                              void* d_out, int out_size, void* d_ws, size_t ws_size,
                              hipStream_t stream) {
    (void)in_sizes; (void)n_in; (void)out_size;
    const float* hidden = (const float*)d_in[0];
    const float* cosp   = (const float*)d_in[1];
    const float* sinp   = (const float*)d_in[2];
    const float* Wq     = (const float*)d_in[3];
    const float* Wk     = (const float*)d_in[4];
    const float* Wv     = (const float*)d_in[5];
    const float* Wo     = (const float*)d_in[6];
    const float* qw     = (const float*)d_in[7];
    const float* kw     = (const float*)d_in[8];
    float* out = (float*)d_out;

    char* p = (char*)d_ws;
    u16* h_bf   = (u16*)p; p += (size_t)8388608 * 2;   // hidden bf16 (4096x2048)
    u16* Wqk_bf = (u16*)p; p += (size_t)17825792 * 2;  // Wq||Wk (8704x2048)
    u16* Wv_bf  = (u16*)p; p += (size_t)1048576 * 2;   // Wv (512x2048)
    u16* Wo_bf  = (u16*)p; p += (size_t)8388608 * 2;   // Wo (2048x4096)
    u16* qgk    = (u16*)p; p += (size_t)35651584 * 2;  // (4096x8704)
    u16* v_t    = (u16*)p; p += (size_t)2097152 * 2;   // V^T (512x4096)
    u16* q_f    = (u16*)p; p += (size_t)16777216 * 2;  // (2,16,2048,256)
    u16* k_f    = (u16*)p; p += (size_t)2097152 * 2;   // (2,2,2048,256)
    u16* attn_g = (u16*)p; p += (size_t)16777216 * 2;  // (4096x4096)
    if ((size_t)(p - (char*)d_ws) > ws_size) return;

    cast_all<<<2048, 256, 0, stream>>>(hidden, Wq, Wk, Wv, Wo,
                                       h_bf, Wqk_bf, Wv_bf, Wo_bf);

    // qgk = hidden @ [Wq;Wk]^T   (4096 x 8704)  -- ring-3 lead-2, GROUP_M=8
    gemm_pipe<1, 256><<<dim3(1088), 512, 0, stream>>>(h_bf, Wqk_bf, qgk, 4096, 8704, 2048, 34);
    // v_t = Wv @ hidden^T        (512 x 4096)
    gemm_bt<1><<<dim3(32, 4), 256, 0, stream>>>(Wv_bf, h_bf, v_t, 512, 4096, 2048);

    norm_rope<<<dim3(1024, 18), 256, 0, stream>>>(qgk, cosp, sinp, qw, kw, q_f, k_f);

    attn_fused<<<dim3(512), 512, 0, stream>>>(q_f, k_f, v_t, qgk, attn_g);

    // out = attn_g @ Wo^T        (4096 x 2048) fp32 -- ring-3 lead-2, GROUP_M=8
    gemm_pipe<0, 128><<<dim3(512), 512, 0, stream>>>(attn_g, Wo_bf, out, 4096, 2048, 4096, 16);
}

// Round 7
// 577.873 us; speedup vs baseline: 1.3741x; 1.3741x over previous
//
#include <hip/hip_runtime.h>
#include <stdint.h>

typedef unsigned short u16;
typedef __bf16 bf16x8 __attribute__((ext_vector_type(8)));
typedef float f32x4 __attribute__((ext_vector_type(4)));
typedef u16 u16x4 __attribute__((ext_vector_type(4)));
typedef u16 u16x8 __attribute__((ext_vector_type(8)));

__device__ __forceinline__ u16 f2b(float f) {  // fp32 -> bf16 bits, RNE
    unsigned u = __builtin_bit_cast(unsigned, f);
    u = u + 0x7FFFu + ((u >> 16) & 1u);
    return (u16)(u >> 16);
}
__device__ __forceinline__ float b2f(u16 b) {
    return __builtin_bit_cast(float, (unsigned)b << 16);
}

// async global->LDS, 16B per lane. LDS dest = wave-uniform base + lane*16.
__device__ __forceinline__ void glds16(const u16* g, u16* l) {
    __builtin_amdgcn_global_load_lds(
        (const __attribute__((address_space(1))) void*)g,
        (__attribute__((address_space(3))) void*)l,
        16, 0, 0);
}

template <int N> __device__ __forceinline__ void waitvm() {
    if constexpr (N == 0)      asm volatile("s_waitcnt vmcnt(0)" ::: "memory");
    else if constexpr (N == 2) asm volatile("s_waitcnt vmcnt(2)" ::: "memory");
    else if constexpr (N == 3) asm volatile("s_waitcnt vmcnt(3)" ::: "memory");
    else if constexpr (N == 4) asm volatile("s_waitcnt vmcnt(4)" ::: "memory");
    else if constexpr (N == 6) asm volatile("s_waitcnt vmcnt(6)" ::: "memory");
    else if constexpr (N == 8) asm volatile("s_waitcnt vmcnt(8)" ::: "memory");
}

// ---------------------------------------------------------------- fused cast fp32->bf16
__global__ __launch_bounds__(256) void cast_all(const float* __restrict__ h,
                                                const float* __restrict__ wq,
                                                const float* __restrict__ wk,
                                                const float* __restrict__ wv,
                                                const float* __restrict__ wo,
                                                u16* __restrict__ h_bf,
                                                u16* __restrict__ wqk_bf,
                                                u16* __restrict__ wv_bf,
                                                u16* __restrict__ wo_bf) {
    const long total  = 35651584;  // elems
    const long stride = (long)gridDim.x * 256 * 4;
    for (long i = ((long)blockIdx.x * 256 + threadIdx.x) * 4; i < total; i += stride) {
        const float* s; u16* d; long off;
        if (i < 8388608)        { s = h;  d = h_bf;             off = i; }
        else if (i < 25165824)  { s = wq; d = wqk_bf;           off = i - 8388608; }
        else if (i < 26214400)  { s = wk; d = wqk_bf + 16777216; off = i - 25165824; }
        else if (i < 27262976)  { s = wv; d = wv_bf;            off = i - 26214400; }
        else                    { s = wo; d = wo_bf;            off = i - 27262976; }
        f32x4 v = *(const f32x4*)(s + off);
        u16x4 o;
        o.x = f2b(v.x); o.y = f2b(v.y); o.z = f2b(v.z); o.w = f2b(v.w);
        *(u16x4*)(d + off) = o;
    }
}

// ---------------------------------------------------------------- GEMM C = A * Bt^T  (legacy 128x128)
template <int OUT_BF16>
__global__ __launch_bounds__(256) void gemm_bt(const u16* __restrict__ A,
                                               const u16* __restrict__ Bt,
                                               void* __restrict__ Cout,
                                               int M, int N, int K) {
    __shared__ u16 As[128 * 32];
    __shared__ u16 Bs[128 * 32];
    const int tid  = threadIdx.x;
    const int w    = tid >> 6;
    const int lane = tid & 63;
    const int quad = lane >> 4;
    const int ml   = lane & 15;
    const long bm  = (long)blockIdx.y * 128;
    const long bn  = (long)blockIdx.x * 128;
    const int wm   = (w >> 1) * 64;
    const int wn   = (w & 1) * 64;
    const int grow = lane >> 2;
    const int gcol = (lane & 3) * 8;

    const u16* Ag = A  + (bm + w * 16 + grow) * (long)K + gcol;
    const u16* Bg = Bt + (bn + w * 16 + grow) * (long)K + gcol;
    u16* lAs0 = &As[(w * 16) * 32];
    u16* lAs1 = &As[(64 + w * 16) * 32];
    u16* lBs0 = &Bs[(w * 16) * 32];
    u16* lBs1 = &Bs[(64 + w * 16) * 32];

    const f32x4 fz = {0.f, 0.f, 0.f, 0.f};
    f32x4 acc[4][4];
#pragma unroll
    for (int i = 0; i < 4; ++i)
#pragma unroll
        for (int j = 0; j < 4; ++j) acc[i][j] = fz;

    for (int k0 = 0; k0 < K; k0 += 32) {
        __syncthreads();
        glds16(Ag + k0,                lAs0);
        glds16(Ag + 64 * (long)K + k0, lAs1);
        glds16(Bg + k0,                lBs0);
        glds16(Bg + 64 * (long)K + k0, lBs1);
        __builtin_amdgcn_s_waitcnt(0);
        __syncthreads();
        bf16x8 af[4], bfr[4];
#pragma unroll
        for (int mt = 0; mt < 4; ++mt)
            af[mt] = *(const bf16x8*)&As[(wm + mt * 16 + ml) * 32 + quad * 8];
#pragma unroll
        for (int nt = 0; nt < 4; ++nt)
            bfr[nt] = *(const bf16x8*)&Bs[(wn + nt * 16 + ml) * 32 + quad * 8];
#pragma unroll
        for (int mt = 0; mt < 4; ++mt)
#pragma unroll
            for (int nt = 0; nt < 4; ++nt)
                acc[mt][nt] = __builtin_amdgcn_mfma_f32_16x16x32_bf16(
                    af[mt], bfr[nt], acc[mt][nt], 0, 0, 0);
    }
#pragma unroll
    for (int mt = 0; mt < 4; ++mt)
#pragma unroll
        for (int nt = 0; nt < 4; ++nt)
#pragma unroll
            for (int r = 0; r < 4; ++r) {
                long row = bm + wm + mt * 16 + quad * 4 + r;
                long col = bn + wn + nt * 16 + ml;
                float v = acc[mt][nt][r];
                if (OUT_BF16) ((u16*)Cout)[row * N + col] = f2b(v);
                else          ((float*)Cout)[row * N + col] = v;
            }
}

// ---------------------------------------------------------------- GEMM pipe v2: ring-3, lead-2, 1 barrier/step
// (unchanged -- verified: FETCH 144MB, conflicts 0, 862 TF)
template <int OUT_BF16, int BN>
__global__ __launch_bounds__(512, 4) void gemm_pipe(const u16* __restrict__ A,
                                                    const u16* __restrict__ Bt,
                                                    void* __restrict__ Cout,
                                                    int M, int N, int K, int nbx) {
    (void)M;
    constexpr int NF  = BN / 64;
    constexpr int ASZ = 128 * 32;
    constexpr int BSZ = BN * 32;
    constexpr int LPT = 1 + BN / 128;
    __shared__ u16 sm[3][ASZ + BSZ];

    const int tid  = threadIdx.x;
    const int w    = tid >> 6;
    const int lane = tid & 63;
    const int quad = lane >> 4;
    const int ml   = lane & 15;
    const int wm   = (w >> 2) * 64;
    const int wn   = (w & 3) * (BN / 4);

    const int nwg = gridDim.x;
    const int q8 = nwg >> 3, r8 = nwg & 7;
    const int xcd = blockIdx.x & 7, loc = blockIdx.x >> 3;
    const int wg  = (xcd < r8 ? xcd * (q8 + 1) : r8 * (q8 + 1) + (xcd - r8) * q8) + loc;
    const int per = nbx * 8;
    const int gid = wg / per, win = wg % per;
    const long bm = (long)(gid * 8 + (win & 7)) * 128;
    const long bn = (long)(win >> 3) * BN;

    const int  srow = w * 16 + (lane >> 2);
    const int  scc  = (lane & 3) ^ ((lane >> 3) & 3);
    const u16* Ag0  = A  + (bm + srow) * (long)K + scc * 8;
    const u16* Bg0  = Bt + (bn + srow) * (long)K + scc * 8;
    const u16* Bg1  = (BN == 256) ? Bg0 + 128 * (long)K : Bg0;
    const int  ldsw = w * 512;

    const int ccr  = quad ^ ((ml >> 1) & 3);
    const int aoff = (wm + ml) * 32 + ccr * 8;
    const int boff = (wn + ml) * 32 + ccr * 8;

    const f32x4 fz = {0.f, 0.f, 0.f, 0.f};
    f32x4 acc[4][NF];
#pragma unroll
    for (int i = 0; i < 4; ++i)
#pragma unroll
        for (int j = 0; j < NF; ++j) acc[i][j] = fz;

    const int NT = K >> 5;

#define STAGE(tt)                                                      \
    {                                                                  \
        u16* base = &sm[(tt) % 3][0];                                  \
        const long ko = (long)(tt) * 32;                               \
        glds16(Ag0 + ko, base + ldsw);                                 \
        glds16(Bg0 + ko, base + ASZ + ldsw);                           \
        if (BN == 256) glds16(Bg1 + ko, base + ASZ + 4096 + ldsw);     \
    }

    STAGE(0); STAGE(1);

    for (int t = 0; t < NT; ++t) {
        if (t + 1 < NT) waitvm<LPT>();
        else            waitvm<0>();
        __builtin_amdgcn_s_barrier();
        __builtin_amdgcn_sched_barrier(0);
        if (t + 2 < NT) STAGE(t + 2);

        const u16* Ab = &sm[t % 3][0];
        const u16* Bb = Ab + ASZ;
        bf16x8 af[4], bfr[NF];
#pragma unroll
        for (int mt = 0; mt < 4; ++mt)
            af[mt] = *(const bf16x8*)(Ab + aoff + mt * 512);
#pragma unroll
        for (int nt = 0; nt < NF; ++nt)
            bfr[nt] = *(const bf16x8*)(Bb + boff + nt * 512);

        __builtin_amdgcn_s_setprio(1);
#pragma unroll
        for (int mt = 0; mt < 4; ++mt)
#pragma unroll
            for (int nt = 0; nt < NF; ++nt)
                acc[mt][nt] = __builtin_amdgcn_mfma_f32_16x16x32_bf16(
                    af[mt], bfr[nt], acc[mt][nt], 0, 0, 0);
        __builtin_amdgcn_s_setprio(0);
    }
#undef STAGE

#pragma unroll
    for (int mt = 0; mt < 4; ++mt)
#pragma unroll
        for (int nt = 0; nt < NF; ++nt)
#pragma unroll
            for (int r = 0; r < 4; ++r) {
                long row = bm + wm + mt * 16 + quad * 4 + r;
                long col = bn + wn + nt * 16 + ml;
                float v = acc[mt][nt][r];
                if (OUT_BF16) ((u16*)Cout)[row * N + col] = f2b(v);
                else          ((float*)Cout)[row * N + col] = v;
            }
}

// ---------------------------------------------------------------- RMSNorm + RoPE + relayout
__global__ __launch_bounds__(256) void norm_rope(const u16* __restrict__ qgk,
                                                 const float* __restrict__ cosp,
                                                 const float* __restrict__ sinp,
                                                 const float* __restrict__ qw,
                                                 const float* __restrict__ kw,
                                                 u16* __restrict__ qf,
                                                 u16* __restrict__ kf) {
    const int t = blockIdx.x * 4 + (threadIdx.x >> 6);
    const int u = blockIdx.y;
    const int lane = threadIdx.x & 63;
    const int b = t >> 11, s = t & 2047;
    const u16* src; const float* wgt; u16* dst;
    if (u < 16) {
        src = qgk + (long)t * 8704 + u * 512;
        wgt = qw;
        dst = qf + ((long)(b * 16 + u) * 2048 + s) * 256;
    } else {
        int kh = u - 16;
        src = qgk + (long)t * 8704 + 8192 + kh * 256;
        wgt = kw;
        dst = kf + ((long)(b * 2 + kh) * 2048 + s) * 256;
    }
    const int d0 = lane * 4;
    u16x4 raw = *(const u16x4*)(src + d0);
    float x0 = b2f(raw.x), x1 = b2f(raw.y), x2 = b2f(raw.z), x3 = b2f(raw.w);
    float ss = x0 * x0 + x1 * x1 + x2 * x2 + x3 * x3;
    for (int off = 32; off; off >>= 1) ss += __shfl_xor(ss, off, 64);
    float inv = rsqrtf(ss * (1.0f / 256.0f) + 1e-6f);
    float n0 = x0 * inv * wgt[d0 + 0];
    float n1 = x1 * inv * wgt[d0 + 1];
    float n2 = x2 * inv * wgt[d0 + 2];
    float n3 = x3 * inv * wgt[d0 + 3];
    float p0 = __shfl_xor(n0, 8, 64);
    float p1 = __shfl_xor(n1, 8, 64);
    float p2 = __shfl_xor(n2, 8, 64);
    float p3 = __shfl_xor(n3, 8, 64);
    if (lane < 16) {
        f32x4 c  = *(const f32x4*)(cosp + (long)t * 64 + d0);
        f32x4 sn = *(const f32x4*)(sinp + (long)t * 64 + d0);
        float sgn = (lane < 8) ? -1.f : 1.f;
        n0 = n0 * c[0] + sgn * p0 * sn[0];
        n1 = n1 * c[1] + sgn * p1 * sn[1];
        n2 = n2 * c[2] + sgn * p2 * sn[2];
        n3 = n3 * c[3] + sgn * p3 * sn[3];
    }
    const float qs = (u < 16) ? 0.0625f : 1.0f;
    n0 *= qs; n1 *= qs; n2 *= qs; n3 *= qs;
    u16x4 o;
    o.x = f2b(n0); o.y = f2b(n1); o.z = f2b(n2); o.w = f2b(n3);
    *(u16x4*)(dst + d0) = o;
}

// ---------------------------------------------------------------- flash attention + gate (v4)
// Fixes for v3's regression (L2 thrash + residency imbalance):
// (a) XCD-locality: bid&7 = XCD; each (b,kh) combo pinned to an XCD PAIR ->
//     per-XCD K/V working set 2 MB < 4 MB L2 (v3: 12 MB -> 445 MB HBM refetch).
// (b) Balanced pairing: block does q-tiles qtA and 15-qtA sequentially ->
//     nkt_total = 34 for EVERY block; grid 256 = 1 block/CU, makespan = mean.
// (c) Double-buffered K/V (144 KiB LDS, affordable at 1 block/CU): stage kt+1
//     right after the single per-tile barrier; vmcnt(0) at next tile-top is a
//     full compute phase (~4 kcyc >> 900) after issue -> latency hidden,
//     1 barrier/tile, no mid-tile K/V split.
// Same verified XOR swizzle (rule #21) and fragment/epilogue math as v2/v3.
__global__ __launch_bounds__(512, 2) void attn_fused(const u16* __restrict__ qf,
                                                     const u16* __restrict__ kf,
                                                     const u16* __restrict__ vt,
                                                     const u16* __restrict__ qgk,
                                                     u16* __restrict__ attn_g) {
    __shared__ u16 Ks[2][64 * 256];   // [buf][key][d]  64 KiB, swizzled
    __shared__ u16 Vt[2][256 * 64];   // [buf][d][key]  64 KiB, swizzled
    __shared__ u16 P[128 * 64];       // [q][key]       16 KiB, wave-private rows
    const int bid  = blockIdx.x;
    const int xcd  = bid & 7;          // round-robin XCD id (heuristic)
    const int slot = bid >> 3;         // 0..31
    const int combo = xcd >> 1;        // 2 XCDs per (b,kh) combo
    const int b  = combo >> 1;
    const int kh = combo & 1;
    const int idx = ((xcd & 1) << 5) | slot;   // 0..63 within combo
    const int h   = kh * 8 + (idx & 7);
    const int qtA = idx >> 3;                  // 0..7; paired with 15-qtA
    const int tid = threadIdx.x;
    const int w = tid >> 6, lane = tid & 63;
    const int quad = lane >> 4, ml = lane & 15;
    const int wh = w >> 2, wq = w & 3;
    const int m7 = ml & 7;

    const u16* kbp = kf + (long)(b * 2 + kh) * 2048 * 256;
    const u16* vbp = vt + (long)kh * 256 * 4096 + (long)b * 2048;

    // staging thread->slot mapping (swizzled SOURCE, linear LDS dest, rule #21)
    const int krow7 = (tid >> 5) & 7;
    const int kswz  = (tid & 31) ^ krow7;
    const int vrow7 = (tid >> 3) & 7;
    const int vswz  = (tid & 7) ^ vrow7;
    const int krow  = tid >> 5;                // 0..15 per issue
    const int vrow  = tid >> 3;                // 0..63 per issue

#define ASTAGE(tt)                                                        \
    {                                                                     \
        u16* kb_ = &Ks[(tt) & 1][0];                                      \
        u16* vb_ = &Vt[(tt) & 1][0];                                      \
        const int kb0 = (tt) * 64;                                        \
        _Pragma("unroll")                                                 \
        for (int i = 0; i < 4; ++i)                                       \
            glds16(kbp + (long)(kb0 + i * 16 + krow) * 256 + kswz * 8,    \
                   kb_ + i * 4096 + w * 512);                             \
        _Pragma("unroll")                                                 \
        for (int i = 0; i < 4; ++i)                                       \
            glds16(vbp + (long)(i * 64 + vrow) * 4096 + kb0 + vswz * 8,   \
                   vb_ + i * 4096 + w * 512);                             \
    }

    const f32x4 fz = {0.f, 0.f, 0.f, 0.f};

#pragma unroll 1
    for (int seg = 0; seg < 2; ++seg) {
        const int qt = seg ? (15 - qtA) : qtA;
        const int qrow = qt * 128 + wh * 64 + wq * 16;
        const int dtile = 2 * qt + wh;     // wave's diagonal k-tile

        const u16* qptr = qf + ((long)(b * 16 + h) * 2048 + qrow + ml) * 256;
        bf16x8 qfrag[8];
#pragma unroll
        for (int dd = 0; dd < 8; ++dd)
            qfrag[dd] = *(const bf16x8*)(qptr + dd * 32 + quad * 8);

        f32x4 oacc[16];
#pragma unroll
        for (int i = 0; i < 16; ++i) oacc[i] = fz;
        float lsum[4] = {0.f, 0.f, 0.f, 0.f};

        const int nkt = 2 * qt + 2;  // causal: k-tiles 0 .. 2qt+1
        ASTAGE(0);

        for (int kt = 0; kt < nkt; ++kt) {
            waitvm<0>();                      // own tile-kt loads done (issued 1 tile ago)
            __builtin_amdgcn_s_barrier();     // all waves' slices visible; old buf free
            __builtin_amdgcn_sched_barrier(0);
            if (kt + 1 < nkt) ASTAGE(kt + 1); // into buf (kt+1)&1 == (kt-1)&1: safe

            const u16* Kb = &Ks[kt & 1][0];
            const u16* Vb = &Vt[kt & 1][0];

            // ---- S = Q K^T (pre-scaled q => sacc is the final score)
            f32x4 sacc[4];
#pragma unroll
            for (int i = 0; i < 4; ++i) sacc[i] = fz;
#pragma unroll
            for (int dd = 0; dd < 8; ++dd) {
                const int ck = (dd * 4 + quad) ^ m7;
                bf16x8 kf0 = *(const bf16x8*)&Kb[(0 * 16 + ml) * 256 + ck * 8];
                bf16x8 kf1 = *(const bf16x8*)&Kb[(1 * 16 + ml) * 256 + ck * 8];
                bf16x8 kf2 = *(const bf16x8*)&Kb[(2 * 16 + ml) * 256 + ck * 8];
                bf16x8 kf3 = *(const bf16x8*)&Kb[(3 * 16 + ml) * 256 + ck * 8];
                __builtin_amdgcn_s_setprio(1);
                sacc[0] = __builtin_amdgcn_mfma_f32_16x16x32_bf16(qfrag[dd], kf0, sacc[0], 0, 0, 0);
                sacc[1] = __builtin_amdgcn_mfma_f32_16x16x32_bf16(qfrag[dd], kf1, sacc[1], 0, 0, 0);
                sacc[2] = __builtin_amdgcn_mfma_f32_16x16x32_bf16(qfrag[dd], kf2, sacc[2], 0, 0, 0);
                sacc[3] = __builtin_amdgcn_mfma_f32_16x16x32_bf16(qfrag[dd], kf3, sacc[3], 0, 0, 0);
                __builtin_amdgcn_s_setprio(0);
            }

            // ---- fixed-shift softmax: p = exp(s - 16), no shuffles, no rescale
            const bool maskt = (kt >= dtile);
#pragma unroll
            for (int nt = 0; nt < 4; ++nt)
#pragma unroll
                for (int r = 0; r < 4; ++r) {
                    float sv = sacc[nt][r];
                    if (maskt) {
                        int rel = wq * 16 + quad * 4 + r + (dtile - kt) * 64;
                        sv = (nt * 16 + ml > rel) ? -1e30f : sv;
                    }
                    float pv = __expf(sv - 16.0f);
                    lsum[r] += pv;
                    const int prow = w * 16 + quad * 4 + r;
                    const int chk = (nt * 2 + (ml >> 3)) ^ ((quad * 4 + r) & 7);
                    P[prow * 64 + chk * 8 + m7] = f2b(pv);
                }

            // ---- O += P V   (P rows wave-private; V ready since tile-top barrier)
#pragma unroll
            for (int ks = 0; ks < 2; ++ks) {
                const int ck = (ks * 4 + quad) ^ m7;
                bf16x8 pfrag = *(const bf16x8*)&P[(w * 16 + ml) * 64 + ck * 8];
                __builtin_amdgcn_s_setprio(1);
#pragma unroll
                for (int dt = 0; dt < 16; ++dt) {
                    bf16x8 vfrag = *(const bf16x8*)&Vb[(dt * 16 + ml) * 64 + ck * 8];
                    oacc[dt] = __builtin_amdgcn_mfma_f32_16x16x32_bf16(pfrag, vfrag, oacc[dt], 0, 0, 0);
                }
                __builtin_amdgcn_s_setprio(0);
            }
        }

        // ---- deferred row-sum reduction (16 lanes of each quad share a row)
#pragma unroll
        for (int off = 1; off < 16; off <<= 1)
#pragma unroll
            for (int r = 0; r < 4; ++r) lsum[r] += __shfl_xor(lsum[r], off, 64);

        // ---- epilogue: 1/l, sigmoid gate, store bf16 (4096 x 4096, col = h*256+d)
#pragma unroll
        for (int dt = 0; dt < 16; ++dt)
#pragma unroll
            for (int r = 0; r < 4; ++r) {
                int srow = qrow + quad * 4 + r;
                long tok = (long)b * 2048 + srow;
                int d = dt * 16 + ml;
                float o = oacc[dt][r] / lsum[r];
                float g = b2f(qgk[tok * 8704 + h * 512 + 256 + d]);
                float gv = o / (1.f + __expf(-g));
                attn_g[tok * 4096 + h * 256 + d] = f2b(gv);
            }
    }
#undef ASTAGE
}

// ---------------------------------------------------------------- launch
extern "C" void kernel_launch(void* const* d_in, const int* in_sizes, int n_in,
                              void* d_out, int out_size, void* d_ws, size_t ws_size,
                              hipStream_t stream) {
    (void)in_sizes; (void)n_in; (void)out_size;
    const float* hidden = (const float*)d_in[0];
    const float* cosp   = (const float*)d_in[1];
    const float* sinp   = (const float*)d_in[2];
    const float* Wq     = (const float*)d_in[3];
    const float* Wk     = (const float*)d_in[4];
    const float* Wv     = (const float*)d_in[5];
    const float* Wo     = (const float*)d_in[6];
    const float* qw     = (const float*)d_in[7];
    const float* kw     = (const float*)d_in[8];
    float* out = (float*)d_out;

    char* p = (char*)d_ws;
    u16* h_bf   = (u16*)p; p += (size_t)8388608 * 2;   // hidden bf16 (4096x2048)
    u16* Wqk_bf = (u16*)p; p += (size_t)17825792 * 2;  // Wq||Wk (8704x2048)
    u16* Wv_bf  = (u16*)p; p += (size_t)1048576 * 2;   // Wv (512x2048)
    u16* Wo_bf  = (u16*)p; p += (size_t)8388608 * 2;   // Wo (2048x4096)
    u16* qgk    = (u16*)p; p += (size_t)35651584 * 2;  // (4096x8704)
    u16* v_t    = (u16*)p; p += (size_t)2097152 * 2;   // V^T (512x4096)
    u16* q_f    = (u16*)p; p += (size_t)16777216 * 2;  // (2,16,2048,256)
    u16* k_f    = (u16*)p; p += (size_t)2097152 * 2;   // (2,2,2048,256)
    u16* attn_g = (u16*)p; p += (size_t)16777216 * 2;  // (4096x4096)
    if ((size_t)(p - (char*)d_ws) > ws_size) return;

    cast_all<<<2048, 256, 0, stream>>>(hidden, Wq, Wk, Wv, Wo,
                                       h_bf, Wqk_bf, Wv_bf, Wo_bf);

    // qgk = hidden @ [Wq;Wk]^T   (4096 x 8704)  -- ring-3 lead-2, GROUP_M=8
    gemm_pipe<1, 256><<<dim3(1088), 512, 0, stream>>>(h_bf, Wqk_bf, qgk, 4096, 8704, 2048, 34);
    // v_t = Wv @ hidden^T        (512 x 4096)
    gemm_bt<1><<<dim3(32, 4), 256, 0, stream>>>(Wv_bf, h_bf, v_t, 512, 4096, 2048);

    norm_rope<<<dim3(1024, 18), 256, 0, stream>>>(qgk, cosp, sinp, qw, kw, q_f, k_f);

    attn_fused<<<dim3(256), 512, 0, stream>>>(q_f, k_f, v_t, qgk, attn_g);

    // out = attn_g @ Wo^T        (4096 x 2048) fp32 -- ring-3 lead-2, GROUP_M=8
    gemm_pipe<0, 128><<<dim3(512), 512, 0, stream>>>(attn_g, Wo_bf, out, 4096, 2048, 4096, 16);
}